// Round 5
// baseline (186.858 us; speedup 1.0000x reference)
//
#include <hip/hip_runtime.h>
#include <hip/hip_bf16.h>
#include <math.h>

#define BSZ 2
#define NQ 4096
#define DIM 768
#define HEADS 6
#define POINTS 4
#define HD 128
#define HW_DIM 64
#define NV (HW_DIM*HW_DIM)
#define M_TOTAL (BSZ*NQ)   // 8192
#define KDIM 768

#define BM 64
#define BN 128
#define BKK 64
#define NBLK_M (M_TOTAL/BM)   // 128
#define NBLK_N (DIM/BN)       // 6
#define GEMM_GRID (NBLK_M*NBLK_N) // 768
#define LN_BLOCKS (M_TOTAL/4)     // 2048
#define TR_BLOCKS (576+576+72)    // 1224
#define SMALL_BLOCKS (M_TOTAL/64) // 128

// double-buffered LDS (u16 counts)
#define A_TILE (BM*BKK)            // 4096
#define B_TILE (BN*BKK)            // 8192
#define SMEM_U16 (2*(A_TILE+B_TILE)) // 24576 u16 = 48 KB

typedef __attribute__((ext_vector_type(8))) short bf16x8;
typedef __attribute__((ext_vector_type(4))) float f32x4;
typedef unsigned int u32;
typedef unsigned short u16;

__device__ inline u16 f2bf(float f) {
    union { float f; u32 u; } v; v.f = f;
    u32 r = v.u + 0x7fffu + ((v.u >> 16) & 1u);
    return (u16)(r >> 16);
}

#define GLD16(g, l) __builtin_amdgcn_global_load_lds( \
    (const __attribute__((address_space(1))) u32*)(g), \
    (__attribute__((address_space(3))) u32*)(l), 16, 0, 0)

// ============ K1: LN(+feat cvt) and weight transposes, union grid ==========
__global__ __launch_bounds__(256) void prep_kernel(
        const float* __restrict__ x, const float* __restrict__ lnw,
        const float* __restrict__ lnb, u16* __restrict__ q,
        const float* __restrict__ feat, u16* __restrict__ feat_bf,
        const float* __restrict__ vp_w,  u16* __restrict__ vp_wt,
        const float* __restrict__ out_w, u16* __restrict__ out_wt,
        const float* __restrict__ off_w, const float* __restrict__ aw_w,
        u16* __restrict__ oaw_wt) {
    int b = blockIdx.x;
    if (b < LN_BLOCKS) {
        int wave = threadIdx.x >> 6, lane = threadIdx.x & 63;
        int row = b * 4 + wave;
        int c = lane * 4;
        const float* xr = x + (size_t)row * DIM;
        const float* fr = feat + (size_t)row * DIM;
        float4 v0 = *(const float4*)(xr + c);
        float4 v1 = *(const float4*)(xr + c + 256);
        float4 v2 = *(const float4*)(xr + c + 512);
        float4 f0 = *(const float4*)(fr + c);
        float4 f1 = *(const float4*)(fr + c + 256);
        float4 f2 = *(const float4*)(fr + c + 512);
        u16* fb = feat_bf + (size_t)row * DIM;
        ushort4 fo;
        fo.x = f2bf(f0.x); fo.y = f2bf(f0.y); fo.z = f2bf(f0.z); fo.w = f2bf(f0.w);
        *(ushort4*)(fb + c) = fo;
        fo.x = f2bf(f1.x); fo.y = f2bf(f1.y); fo.z = f2bf(f1.z); fo.w = f2bf(f1.w);
        *(ushort4*)(fb + c + 256) = fo;
        fo.x = f2bf(f2.x); fo.y = f2bf(f2.y); fo.z = f2bf(f2.z); fo.w = f2bf(f2.w);
        *(ushort4*)(fb + c + 512) = fo;

        float s  = v0.x+v0.y+v0.z+v0.w + v1.x+v1.y+v1.z+v1.w + v2.x+v2.y+v2.z+v2.w;
        float ss = v0.x*v0.x+v0.y*v0.y+v0.z*v0.z+v0.w*v0.w
                 + v1.x*v1.x+v1.y*v1.y+v1.z*v1.z+v1.w*v1.w
                 + v2.x*v2.x+v2.y*v2.y+v2.z*v2.z+v2.w*v2.w;
        #pragma unroll
        for (int st = 1; st < 64; st <<= 1) {
            s  += __shfl_xor(s,  st, 64);
            ss += __shfl_xor(ss, st, 64);
        }
        float mean = s * (1.0f / DIM);
        float var  = ss * (1.0f / DIM) - mean * mean;
        float rstd = rsqrtf(var + 1e-6f);
        u16* qr = q + (size_t)row * DIM;
        #pragma unroll
        for (int g = 0; g < 3; g++) {
            float4 v = (g == 0) ? v0 : (g == 1) ? v1 : v2;
            int cc = c + g * 256;
            const float4 ww = *(const float4*)(lnw + cc);
            const float4 bb = *(const float4*)(lnb + cc);
            ushort4 o;
            o.x = f2bf((v.x - mean) * rstd * ww.x + bb.x);
            o.y = f2bf((v.y - mean) * rstd * ww.y + bb.y);
            o.z = f2bf((v.z - mean) * rstd * ww.z + bb.z);
            o.w = f2bf((v.w - mean) * rstd * ww.w + bb.w);
            *(ushort4*)(qr + cc) = o;
        }
    } else {
        int t = b - LN_BLOCKS;
        int z, xk, yk;
        if (t < 576)      { z = 0; xk = t % 24; yk = t / 24; }
        else if (t < 1152){ z = 1; t -= 576; xk = t % 24; yk = t / 24; }
        else              { z = 2; t -= 1152; xk = t % 3; yk = t / 3; }
        __shared__ float tile[32][33];
        int n0 = xk * 32, k0 = yk * 32;
        int tx = threadIdx.x & 31, ty = threadIdx.x >> 5;
        const float* src = (z == 0) ? vp_w : (z == 1) ? out_w : nullptr;
        u16* dst = (z == 0) ? vp_wt : (z == 1) ? out_wt : oaw_wt;
        #pragma unroll
        for (int r = 0; r < 4; r++) {
            int k = k0 + ty + r * 8, n = n0 + tx;
            float v = 0.0f;
            if (z < 2) {
                v = src[(size_t)k * DIM + n];
            } else {
                if (n < 48) v = off_w[(size_t)k * 48 + n];
                else if (n < 72) v = aw_w[(size_t)k * 24 + (n - 48)];
            }
            tile[ty + r * 8][tx] = v;
        }
        __syncthreads();
        #pragma unroll
        for (int r = 0; r < 4; r++) {
            int nn = ty + r * 8, kk = tx;
            int drow = n0 + nn;
            if (z == 2 && drow >= 80) continue;
            dst[(size_t)drow * KDIM + k0 + kk] = f2bf(tile[kk][nn]);
        }
    }
}

// ====== big-GEMM body: 64x128 tile, BK=64, double-buffered prefetch ========
__device__ __forceinline__ void gemm_big_body(int b, u16* __restrict__ smem,
        const u16* __restrict__ A, const u16* __restrict__ Bt,
        const float* __restrict__ bias, void* __restrict__ Cout,
        int storeBF16, const float* __restrict__ resid,
        const float* __restrict__ gamma) {
    u16* As = smem;                 // [2][A_TILE]
    u16* Bs = smem + 2 * A_TILE;    // [2][B_TILE]
    int tid = threadIdx.x, w = tid >> 6, lane = tid & 63;
    int lm = lane & 15, quad = lane >> 4;
    int xcd = b & 7, idx = b >> 3;        // idx: 0..95
    int mb = xcd * 16 + idx / NBLK_N;
    int nb = idx % NBLK_N;
    int m0 = mb * BM, n0 = nb * BN;
    int wr = w & 1, wc = w >> 1;

    int srow = lane >> 3;               // 0..7
    int scol = (lane & 7) ^ srow;       // XOR-swizzled source col-block
    const u16* Ab = A + (size_t)m0 * KDIM;
    const u16* Bb = Bt + (size_t)n0 * KDIM;

    f32x4 acc[2][4];
    #pragma unroll
    for (int i = 0; i < 2; i++)
        #pragma unroll
        for (int j = 0; j < 4; j++) acc[i][j] = (f32x4){0.f, 0.f, 0.f, 0.f};

    int aoff[2][2], boff[4][2];
    #pragma unroll
    for (int i = 0; i < 2; i++) {
        int row = wr * 32 + i * 16 + lm;
        #pragma unroll
        for (int kk = 0; kk < 2; kk++)
            aoff[i][kk] = row * BKK + (((quad + 4 * kk) ^ (row & 7)) << 3);
    }
    #pragma unroll
    for (int j = 0; j < 4; j++) {
        int row = wc * 64 + j * 16 + lm;
        #pragma unroll
        for (int kk = 0; kk < 2; kk++)
            boff[j][kk] = row * BKK + (((quad + 4 * kk) ^ (row & 7)) << 3);
    }

    auto stage = [&](int buf, int k0) {
        #pragma unroll
        for (int r = 0; r < 2; r++) {
            int row = r * 32 + w * 8 + srow;
            GLD16(Ab + (size_t)row * KDIM + k0 + scol * 8,
                  As + buf * A_TILE + (r * 32 + w * 8) * BKK);
        }
        #pragma unroll
        for (int r = 0; r < 4; r++) {
            int row = r * 32 + w * 8 + srow;
            GLD16(Bb + (size_t)row * KDIM + k0 + scol * 8,
                  Bs + buf * B_TILE + (r * 32 + w * 8) * BKK);
        }
    };

    stage(0, 0);
    __syncthreads();
    const int NT = KDIM / BKK;          // 12
    for (int t = 0; t < NT; t++) {
        if (t + 1 < NT) stage((t + 1) & 1, (t + 1) * BKK);
        const u16* Ap = As + (t & 1) * A_TILE;
        const u16* Bp = Bs + (t & 1) * B_TILE;
        #pragma unroll
        for (int kk = 0; kk < 2; kk++) {
            bf16x8 af[2], bf[4];
            #pragma unroll
            for (int i = 0; i < 2; i++) af[i] = *(const bf16x8*)(Ap + aoff[i][kk]);
            #pragma unroll
            for (int j = 0; j < 4; j++) bf[j] = *(const bf16x8*)(Bp + boff[j][kk]);
            #pragma unroll
            for (int i = 0; i < 2; i++)
                #pragma unroll
                for (int j = 0; j < 4; j++)
                    acc[i][j] = __builtin_amdgcn_mfma_f32_16x16x32_bf16(af[i], bf[j], acc[i][j], 0, 0, 0);
        }
        __syncthreads();
    }

    #pragma unroll
    for (int j = 0; j < 4; j++) {
        int col = n0 + wc * 64 + j * 16 + lm;
        float bb = bias[col];
        #pragma unroll
        for (int i = 0; i < 2; i++) {
            #pragma unroll
            for (int r = 0; r < 4; r++) {
                int row = m0 + wr * 32 + i * 16 + quad * 4 + r;
                size_t idxo = (size_t)row * DIM + col;
                float v = acc[i][j][r] + bb;
                if (storeBF16) {
                    ((u16*)Cout)[idxo] = f2bf(v);
                } else {
                    ((float*)Cout)[idxo] = resid[idxo] + gamma[col] * v;
                }
            }
        }
    }
}

// ====== small-GEMM body: q[64xK768] * Wt[80xK768]^T, dbuf, fused epilogue ==
// Epilogue computes softmax(24) per row + bilinear corner offsets/weights
// and writes packed records consumed by the sliced sample kernel.
#define SA_TILE (64*32)   // 2048 u16
#define SB_TILE (80*32)   // 2560 u16
__device__ __forceinline__ void gemm_small_body(int mblk,
        u16* __restrict__ smem,
        const u16* __restrict__ A, const u16* __restrict__ Bt,
        const float* __restrict__ b0, const float* __restrict__ b1,
        const float* __restrict__ refp,
        int4* __restrict__ pk_o, float4* __restrict__ pk_w) {
    u16* As2 = smem;                  // [2][SA_TILE]
    u16* Bs2 = smem + 2 * SA_TILE;    // [2][SB_TILE]
    int tid = threadIdx.x, wave = tid >> 6, lane = tid & 63;
    int lm = lane & 15, quad = lane >> 4;
    int m0 = mblk * 64;
    f32x4 acc[5];
    #pragma unroll
    for (int i = 0; i < 5; i++) acc[i] = (f32x4){0.f, 0.f, 0.f, 0.f};
    int lrow = lane >> 2, lcol = (lane & 3) * 8;

    auto stage = [&](int buf, int k0) {
        for (int c = wave; c < 9; c += 4) {
            if (c < 4) {
                GLD16(A + (size_t)(m0 + c * 16 + lrow) * KDIM + k0 + lcol,
                      As2 + buf * SA_TILE + c * 16 * 32);
            } else {
                GLD16(Bt + (size_t)((c - 4) * 16 + lrow) * KDIM + k0 + lcol,
                      Bs2 + buf * SB_TILE + (c - 4) * 16 * 32);
            }
        }
    };

    stage(0, 0);
    __syncthreads();
    const int NT = KDIM / 32;         // 24
    for (int t = 0; t < NT; t++) {
        if (t + 1 < NT) stage((t + 1) & 1, (t + 1) * 32);
        const u16* Ap = As2 + (t & 1) * SA_TILE;
        const u16* Bp = Bs2 + (t & 1) * SB_TILE;
        bf16x8 af = *(const bf16x8*)(Ap + (wave * 16 + lm) * 32 + quad * 8);
        #pragma unroll
        for (int bn = 0; bn < 5; bn++) {
            bf16x8 bv = *(const bf16x8*)(Bp + (bn * 16 + lm) * 32 + quad * 8);
            acc[bn] = __builtin_amdgcn_mfma_f32_16x16x32_bf16(af, bv, acc[bn], 0, 0, 0);
        }
        __syncthreads();
    }

    // ---- epilogue: C[64][80] -> LDS, softmax + corner pack ----
    float* Cs = (float*)smem;           // 64*80*4 = 20 KB (safe: post-loop)
    float* rowm  = Cs + 64 * 80;
    float* rowiv = rowm + 64;
    #pragma unroll
    for (int bn = 0; bn < 5; bn++) {
        int col = bn * 16 + lm;
        float bb = (col < 48) ? b0[col] : ((col < 72) ? b1[col - 48] : 0.0f);
        #pragma unroll
        for (int r = 0; r < 4; r++) {
            int rl = wave * 16 + quad * 4 + r;
            Cs[rl * 80 + col] = acc[bn][r] + bb;
        }
    }
    __syncthreads();
    if (tid < 64) {
        const float* cr = Cs + tid * 80 + 48;
        float m = cr[0];
        #pragma unroll
        for (int i = 1; i < 24; i++) m = fmaxf(m, cr[i]);
        float s = 0.f;
        #pragma unroll
        for (int i = 0; i < 24; i++) s += expf(cr[i] - m);
        rowm[tid] = m;
        rowiv[tid] = 1.0f / s;
    }
    __syncthreads();
    for (int j = tid; j < 64 * 24; j += 256) {
        int rl = j / 24, idx = j - rl * 24;
        int h = idx >> 2, p = idx & 3;
        const float* cr = Cs + rl * 80;
        float ox = cr[h * 8 + p * 2 + 0];
        float oy = cr[h * 8 + p * 2 + 1];
        float aw = expf(cr[48 + idx] - rowm[rl]) * rowiv[rl];
        int grow = m0 + rl;
        float rx = refp[grow * 2 + 0], ry = refp[grow * 2 + 1];
        float x = (rx + ox * (1.0f / HW_DIM)) * HW_DIM - 0.5f;
        float y = (ry + oy * (1.0f / HW_DIM)) * HW_DIM - 0.5f;
        float fx = floorf(x), fy = floorf(y);
        int x0 = (int)fx, y0 = (int)fy;
        int x1 = x0 + 1, y1 = y0 + 1;
        float wx = x - fx, wy = y - fy;
        float vx0 = (x0 >= 0 && x0 < HW_DIM) ? 1.f : 0.f;
        float vx1 = (x1 >= 0 && x1 < HW_DIM) ? 1.f : 0.f;
        float vy0 = (y0 >= 0 && y0 < HW_DIM) ? 1.f : 0.f;
        float vy1 = (y1 >= 0 && y1 < HW_DIM) ? 1.f : 0.f;
        int xc0 = min(max(x0, 0), HW_DIM - 1), xc1 = min(max(x1, 0), HW_DIM - 1);
        int yc0 = min(max(y0, 0), HW_DIM - 1), yc1 = min(max(y1, 0), HW_DIM - 1);
        int base = (grow >> 12) * NV * DIM;
        int4 o;
        o.x = base + (yc0 * HW_DIM + xc0) * DIM;
        o.y = base + (yc0 * HW_DIM + xc1) * DIM;
        o.z = base + (yc1 * HW_DIM + xc0) * DIM;
        o.w = base + (yc1 * HW_DIM + xc1) * DIM;
        float4 wv;
        wv.x = aw * (1.f - wy) * (1.f - wx) * vy0 * vx0;
        wv.y = aw * (1.f - wy) * wx * vy0 * vx1;
        wv.z = aw * wy * (1.f - wx) * vy1 * vx0;
        wv.w = aw * wy * wx * vy1 * vx1;
        pk_o[(size_t)grow * 24 + idx] = o;
        pk_w[(size_t)grow * 24 + idx] = wv;
    }
}

// ============ K2: value-GEMM + offsets/aw-GEMM(+pack), union grid ==========
__global__ __launch_bounds__(256, 3) void gemms_kernel(
        const u16* __restrict__ feat_bf, const u16* __restrict__ vp_wt,
        const float* __restrict__ vp_b, u16* __restrict__ v_bf,
        const u16* __restrict__ q_bf, const u16* __restrict__ oaw_wt,
        const float* __restrict__ off_b, const float* __restrict__ aw_b,
        const float* __restrict__ refp,
        int4* __restrict__ pk_o, float4* __restrict__ pk_w) {
    __shared__ __align__(16) u16 smem[SMEM_U16];   // 48 KB
    int b = blockIdx.x;
    if (b < GEMM_GRID) {
        gemm_big_body(b, smem, feat_bf, vp_wt, vp_b, v_bf, 1, nullptr, nullptr);
    } else {
        gemm_small_body(b - GEMM_GRID, smem, q_bf, oaw_wt, off_b, aw_b,
                        refp, pk_o, pk_w);
    }
}

// ============ K4: out-GEMM with residual epilogue ==========================
__global__ __launch_bounds__(256, 3) void outgemm_kernel(
        const u16* __restrict__ s_bf, const u16* __restrict__ out_wt,
        const float* __restrict__ out_b, float* __restrict__ out_f,
        const float* __restrict__ query, const float* __restrict__ gamma) {
    __shared__ __align__(16) u16 smem[SMEM_U16];
    gemm_big_body(blockIdx.x, smem, s_bf, out_wt, out_b, out_f, 0, query, gamma);
}

// ============ K3: pure sliced gather (packed weights precomputed) ==========
// Grid = 24 combos * 256 query-blocks; combo -> (head, batch, half-of-HD).
// 24 % 8 == 0 keeps each combo on one XCD; per-XCD gather set = 3 slices of
// 512 KB = 1.5 MB < 4 MiB L2. No softmax, no oa: only packed record reads.
#define SMP_QPB 16
#define SMP_COMBOS 24
#define SMP_BLOCKS (SMP_COMBOS * (NQ / SMP_QPB))   // 6144

__global__ __launch_bounds__(256) void sample_kernel(
        const int4* __restrict__ pk_o, const float4* __restrict__ pk_w,
        const u16* __restrict__ v, u16* __restrict__ out) {
    int combo = blockIdx.x % SMP_COMBOS;
    int qblk  = blockIdx.x / SMP_COMBOS;       // 0..255
    int head  = combo % 6;
    int rest  = combo / 6;                      // 0..3
    int batch = rest >> 1;
    int half  = rest & 1;
    int tid  = threadIdx.x;
    int q    = tid >> 4;                        // 0..15
    int lane = tid & 15;                        // 0..15
    int row  = batch * NQ + qblk * SMP_QPB + q;

    __shared__ int4   s_o[SMP_QPB][4];
    __shared__ float4 s_w[SMP_QPB][4];
    if (lane < 4) {
        size_t pidx = (size_t)row * 24 + head * 4 + lane;
        s_o[q][lane] = pk_o[pidx];
        s_w[q][lane] = pk_w[pidx];
    }
    __syncthreads();

    int dbase = head * HD + half * 64 + lane * 4;
    const u16* vb = v + dbase;
    float a0 = 0.f, a1 = 0.f, a2 = 0.f, a3 = 0.f;
    #pragma unroll
    for (int p = 0; p < 4; p++) {
        int4 o = s_o[q][p];
        float4 wv = s_w[q][p];
        uint2 u0 = *(const uint2*)(vb + o.x);
        uint2 u1 = *(const uint2*)(vb + o.y);
        uint2 u2 = *(const uint2*)(vb + o.z);
        uint2 u3 = *(const uint2*)(vb + o.w);
        a0 += wv.x * __uint_as_float(u0.x << 16) + wv.y * __uint_as_float(u1.x << 16)
            + wv.z * __uint_as_float(u2.x << 16) + wv.w * __uint_as_float(u3.x << 16);
        a1 += wv.x * __uint_as_float(u0.x & 0xffff0000u) + wv.y * __uint_as_float(u1.x & 0xffff0000u)
            + wv.z * __uint_as_float(u2.x & 0xffff0000u) + wv.w * __uint_as_float(u3.x & 0xffff0000u);
        a2 += wv.x * __uint_as_float(u0.y << 16) + wv.y * __uint_as_float(u1.y << 16)
            + wv.z * __uint_as_float(u2.y << 16) + wv.w * __uint_as_float(u3.y << 16);
        a3 += wv.x * __uint_as_float(u0.y & 0xffff0000u) + wv.y * __uint_as_float(u1.y & 0xffff0000u)
            + wv.z * __uint_as_float(u2.y & 0xffff0000u) + wv.w * __uint_as_float(u3.y & 0xffff0000u);
    }
    uint2 pack;
    pack.x = (u32)f2bf(a0) | ((u32)f2bf(a1) << 16);
    pack.y = (u32)f2bf(a2) | ((u32)f2bf(a3) << 16);
    *(uint2*)&out[(size_t)row * DIM + dbase] = pack;
}

extern "C" void kernel_launch(void* const* d_in, const int* in_sizes, int n_in,
                              void* d_out, int out_size, void* d_ws, size_t ws_size,
                              hipStream_t stream) {
    const float* query = (const float*)d_in[0];
    const float* refp  = (const float*)d_in[1];
    const float* feat  = (const float*)d_in[2];
    const float* ln_w  = (const float*)d_in[5];
    const float* ln_b  = (const float*)d_in[6];
    const float* vp_w  = (const float*)d_in[7];
    const float* vp_b  = (const float*)d_in[8];
    const float* off_w = (const float*)d_in[9];
    const float* off_b = (const float*)d_in[10];
    const float* aw_w  = (const float*)d_in[11];
    const float* aw_b  = (const float*)d_in[12];
    const float* out_w = (const float*)d_in[13];
    const float* out_b = (const float*)d_in[14];
    const float* gamma = (const float*)d_in[15];

    const size_t MD = (size_t)M_TOTAL * DIM;      // 6291456
    char* ws = (char*)d_ws;
    u16* q_bf    = (u16*)ws;                 ws += MD * 2;
    u16* feat_bf = (u16*)ws;                 ws += MD * 2;
    u16* v_bf    = (u16*)ws;                 ws += MD * 2;
    u16* s_bf    = (u16*)ws;                 ws += MD * 2;
    u16* vp_wt   = (u16*)ws;                 ws += (size_t)DIM * DIM * 2;
    u16* out_wt  = (u16*)ws;                 ws += (size_t)DIM * DIM * 2;
    u16* oaw_wt  = (u16*)ws;                 ws += (size_t)80 * KDIM * 2;
    int4* pk_o   = (int4*)ws;                ws += (size_t)M_TOTAL * 24 * 16;
    float4* pk_w = (float4*)ws;              ws += (size_t)M_TOTAL * 24 * 16;
    float* out_f = (float*)d_out;

    // K1: LN+feat cvt (2048 blocks) + weight transposes (1224 blocks)
    prep_kernel<<<LN_BLOCKS + TR_BLOCKS, 256, 0, stream>>>(
        query, ln_w, ln_b, q_bf, feat, feat_bf,
        vp_w, vp_wt, out_w, out_wt, off_w, aw_w, oaw_wt);
    // K2: value-GEMM (768) + fused offsets/aw-GEMM + softmax/corner pack (128)
    gemms_kernel<<<GEMM_GRID + SMALL_BLOCKS, 256, 0, stream>>>(
        feat_bf, vp_wt, vp_b, v_bf, q_bf, oaw_wt, off_b, aw_b,
        refp, pk_o, pk_w);
    // K3: pure sliced gather, XCD-pinned
    sample_kernel<<<SMP_BLOCKS, 256, 0, stream>>>(pk_o, pk_w, v_bf, s_bf);
    // K4: out = query + gamma * (s @ out_w + out_b)
    outgemm_kernel<<<GEMM_GRID, 256, 0, stream>>>(s_bf, out_wt, out_b, out_f, query, gamma);
}

// Round 6
// 174.438 us; speedup vs baseline: 1.0712x; 1.0712x over previous
//
#include <hip/hip_runtime.h>
#include <hip/hip_bf16.h>
#include <math.h>

#define BSZ 2
#define NQ 4096
#define DIM 768
#define HEADS 6
#define POINTS 4
#define HD 128
#define HW_DIM 64
#define NV (HW_DIM*HW_DIM)
#define M_TOTAL (BSZ*NQ)   // 8192
#define KDIM 768
#define KSPLIT 2
#define KPART (KDIM/KSPLIT)  // 384

#define BM 64
#define BN 128
#define BKK 64
#define NBLK_M (M_TOTAL/BM)   // 128
#define NBLK_N (DIM/BN)       // 6
#define GEMM_GRID (NBLK_M*NBLK_N) // 768
#define LN_BLOCKS (M_TOTAL/4)     // 2048
#define TR_BLOCKS (576+576+72)    // 1224
#define SMALL_BLOCKS (128*KSPLIT) // 256

// double-buffered LDS (u16 counts)
#define A_TILE (BM*BKK)            // 4096
#define B_TILE (BN*BKK)            // 8192
#define SMEM_U16 (2*(A_TILE+B_TILE)) // 24576 u16 = 48 KB

typedef __attribute__((ext_vector_type(8))) short bf16x8;
typedef __attribute__((ext_vector_type(4))) float f32x4;
typedef unsigned int u32;
typedef unsigned short u16;

__device__ inline u16 f2bf(float f) {
    union { float f; u32 u; } v; v.f = f;
    u32 r = v.u + 0x7fffu + ((v.u >> 16) & 1u);
    return (u16)(r >> 16);
}

#define GLD16(g, l) __builtin_amdgcn_global_load_lds( \
    (const __attribute__((address_space(1))) u32*)(g), \
    (__attribute__((address_space(3))) u32*)(l), 16, 0, 0)

// ============ K1: LN(+feat cvt) and weight transposes, union grid ==========
__global__ __launch_bounds__(256) void prep_kernel(
        const float* __restrict__ x, const float* __restrict__ lnw,
        const float* __restrict__ lnb, u16* __restrict__ q,
        const float* __restrict__ feat, u16* __restrict__ feat_bf,
        const float* __restrict__ vp_w,  u16* __restrict__ vp_wt,
        const float* __restrict__ out_w, u16* __restrict__ out_wt,
        const float* __restrict__ off_w, const float* __restrict__ aw_w,
        u16* __restrict__ oaw_wt) {
    int b = blockIdx.x;
    if (b < LN_BLOCKS) {
        int wave = threadIdx.x >> 6, lane = threadIdx.x & 63;
        int row = b * 4 + wave;
        int c = lane * 4;
        const float* xr = x + (size_t)row * DIM;
        const float* fr = feat + (size_t)row * DIM;
        float4 v0 = *(const float4*)(xr + c);
        float4 v1 = *(const float4*)(xr + c + 256);
        float4 v2 = *(const float4*)(xr + c + 512);
        float4 f0 = *(const float4*)(fr + c);
        float4 f1 = *(const float4*)(fr + c + 256);
        float4 f2 = *(const float4*)(fr + c + 512);
        u16* fb = feat_bf + (size_t)row * DIM;
        ushort4 fo;
        fo.x = f2bf(f0.x); fo.y = f2bf(f0.y); fo.z = f2bf(f0.z); fo.w = f2bf(f0.w);
        *(ushort4*)(fb + c) = fo;
        fo.x = f2bf(f1.x); fo.y = f2bf(f1.y); fo.z = f2bf(f1.z); fo.w = f2bf(f1.w);
        *(ushort4*)(fb + c + 256) = fo;
        fo.x = f2bf(f2.x); fo.y = f2bf(f2.y); fo.z = f2bf(f2.z); fo.w = f2bf(f2.w);
        *(ushort4*)(fb + c + 512) = fo;

        float s  = v0.x+v0.y+v0.z+v0.w + v1.x+v1.y+v1.z+v1.w + v2.x+v2.y+v2.z+v2.w;
        float ss = v0.x*v0.x+v0.y*v0.y+v0.z*v0.z+v0.w*v0.w
                 + v1.x*v1.x+v1.y*v1.y+v1.z*v1.z+v1.w*v1.w
                 + v2.x*v2.x+v2.y*v2.y+v2.z*v2.z+v2.w*v2.w;
        #pragma unroll
        for (int st = 1; st < 64; st <<= 1) {
            s  += __shfl_xor(s,  st, 64);
            ss += __shfl_xor(ss, st, 64);
        }
        float mean = s * (1.0f / DIM);
        float var  = ss * (1.0f / DIM) - mean * mean;
        float rstd = rsqrtf(var + 1e-6f);
        u16* qr = q + (size_t)row * DIM;
        #pragma unroll
        for (int g = 0; g < 3; g++) {
            float4 v = (g == 0) ? v0 : (g == 1) ? v1 : v2;
            int cc = c + g * 256;
            const float4 ww = *(const float4*)(lnw + cc);
            const float4 bb = *(const float4*)(lnb + cc);
            ushort4 o;
            o.x = f2bf((v.x - mean) * rstd * ww.x + bb.x);
            o.y = f2bf((v.y - mean) * rstd * ww.y + bb.y);
            o.z = f2bf((v.z - mean) * rstd * ww.z + bb.z);
            o.w = f2bf((v.w - mean) * rstd * ww.w + bb.w);
            *(ushort4*)(qr + cc) = o;
        }
    } else {
        int t = b - LN_BLOCKS;
        int z, xk, yk;
        if (t < 576)      { z = 0; xk = t % 24; yk = t / 24; }
        else if (t < 1152){ z = 1; t -= 576; xk = t % 24; yk = t / 24; }
        else              { z = 2; t -= 1152; xk = t % 3; yk = t / 3; }
        __shared__ float tile[32][33];
        int n0 = xk * 32, k0 = yk * 32;
        int tx = threadIdx.x & 31, ty = threadIdx.x >> 5;
        const float* src = (z == 0) ? vp_w : (z == 1) ? out_w : nullptr;
        u16* dst = (z == 0) ? vp_wt : (z == 1) ? out_wt : oaw_wt;
        #pragma unroll
        for (int r = 0; r < 4; r++) {
            int k = k0 + ty + r * 8, n = n0 + tx;
            float v = 0.0f;
            if (z < 2) {
                v = src[(size_t)k * DIM + n];
            } else {
                if (n < 48) v = off_w[(size_t)k * 48 + n];
                else if (n < 72) v = aw_w[(size_t)k * 24 + (n - 48)];
            }
            tile[ty + r * 8][tx] = v;
        }
        __syncthreads();
        #pragma unroll
        for (int r = 0; r < 4; r++) {
            int nn = ty + r * 8, kk = tx;
            int drow = n0 + nn;
            if (z == 2 && drow >= 80) continue;
            dst[(size_t)drow * KDIM + k0 + kk] = f2bf(tile[kk][nn]);
        }
    }
}

// ====== big-GEMM body: 64x128 tile, BK=64, double-buffered prefetch ========
__device__ __forceinline__ void gemm_big_body(int b, u16* __restrict__ smem,
        const u16* __restrict__ A, const u16* __restrict__ Bt,
        const float* __restrict__ bias, void* __restrict__ Cout,
        int storeBF16, const float* __restrict__ resid,
        const float* __restrict__ gamma) {
    u16* As = smem;                 // [2][A_TILE]
    u16* Bs = smem + 2 * A_TILE;    // [2][B_TILE]
    int tid = threadIdx.x, w = tid >> 6, lane = tid & 63;
    int lm = lane & 15, quad = lane >> 4;
    int xcd = b & 7, idx = b >> 3;        // idx: 0..95
    int mb = xcd * 16 + idx / NBLK_N;
    int nb = idx % NBLK_N;
    int m0 = mb * BM, n0 = nb * BN;
    int wr = w & 1, wc = w >> 1;

    int srow = lane >> 3;               // 0..7
    int scol = (lane & 7) ^ srow;       // XOR-swizzled source col-block
    const u16* Ab = A + (size_t)m0 * KDIM;
    const u16* Bb = Bt + (size_t)n0 * KDIM;

    f32x4 acc[2][4];
    #pragma unroll
    for (int i = 0; i < 2; i++)
        #pragma unroll
        for (int j = 0; j < 4; j++) acc[i][j] = (f32x4){0.f, 0.f, 0.f, 0.f};

    int aoff[2][2], boff[4][2];
    #pragma unroll
    for (int i = 0; i < 2; i++) {
        int row = wr * 32 + i * 16 + lm;
        #pragma unroll
        for (int kk = 0; kk < 2; kk++)
            aoff[i][kk] = row * BKK + (((quad + 4 * kk) ^ (row & 7)) << 3);
    }
    #pragma unroll
    for (int j = 0; j < 4; j++) {
        int row = wc * 64 + j * 16 + lm;
        #pragma unroll
        for (int kk = 0; kk < 2; kk++)
            boff[j][kk] = row * BKK + (((quad + 4 * kk) ^ (row & 7)) << 3);
    }

    auto stage = [&](int buf, int k0) {
        #pragma unroll
        for (int r = 0; r < 2; r++) {
            int row = r * 32 + w * 8 + srow;
            GLD16(Ab + (size_t)row * KDIM + k0 + scol * 8,
                  As + buf * A_TILE + (r * 32 + w * 8) * BKK);
        }
        #pragma unroll
        for (int r = 0; r < 4; r++) {
            int row = r * 32 + w * 8 + srow;
            GLD16(Bb + (size_t)row * KDIM + k0 + scol * 8,
                  Bs + buf * B_TILE + (r * 32 + w * 8) * BKK);
        }
    };

    stage(0, 0);
    __syncthreads();
    const int NT = KDIM / BKK;          // 12
    for (int t = 0; t < NT; t++) {
        if (t + 1 < NT) stage((t + 1) & 1, (t + 1) * BKK);
        const u16* Ap = As + (t & 1) * A_TILE;
        const u16* Bp = Bs + (t & 1) * B_TILE;
        #pragma unroll
        for (int kk = 0; kk < 2; kk++) {
            bf16x8 af[2], bf[4];
            #pragma unroll
            for (int i = 0; i < 2; i++) af[i] = *(const bf16x8*)(Ap + aoff[i][kk]);
            #pragma unroll
            for (int j = 0; j < 4; j++) bf[j] = *(const bf16x8*)(Bp + boff[j][kk]);
            #pragma unroll
            for (int i = 0; i < 2; i++)
                #pragma unroll
                for (int j = 0; j < 4; j++)
                    acc[i][j] = __builtin_amdgcn_mfma_f32_16x16x32_bf16(af[i], bf[j], acc[i][j], 0, 0, 0);
        }
        __syncthreads();
    }

    #pragma unroll
    for (int j = 0; j < 4; j++) {
        int col = n0 + wc * 64 + j * 16 + lm;
        float bb = bias[col];
        #pragma unroll
        for (int i = 0; i < 2; i++) {
            #pragma unroll
            for (int r = 0; r < 4; r++) {
                int row = m0 + wr * 32 + i * 16 + quad * 4 + r;
                size_t idxo = (size_t)row * DIM + col;
                float v = acc[i][j][r] + bb;
                if (storeBF16) {
                    ((u16*)Cout)[idxo] = f2bf(v);
                } else {
                    ((float*)Cout)[idxo] = resid[idxo] + gamma[col] * v;
                }
            }
        }
    }
}

// ====== small-GEMM body: q[M][Kpart] * Wt[80][Kpart], double-buffered ======
#define SA_TILE (64*32)   // 2048 u16
#define SB_TILE (80*32)   // 2560 u16
__device__ __forceinline__ void gemm_small_body(int mblk, int part,
        u16* __restrict__ smem,
        const u16* __restrict__ A, const u16* __restrict__ Bt,
        const float* __restrict__ b0, const float* __restrict__ b1,
        float* __restrict__ C) {
    u16* As2 = smem;                  // [2][SA_TILE]
    u16* Bs2 = smem + 2 * SA_TILE;    // [2][SB_TILE]
    int tid = threadIdx.x, wave = tid >> 6, lane = tid & 63;
    int lm = lane & 15, quad = lane >> 4;
    int m0 = mblk * 64;
    int kbase = part * KPART;
    f32x4 acc[5];
    #pragma unroll
    for (int i = 0; i < 5; i++) acc[i] = (f32x4){0.f, 0.f, 0.f, 0.f};
    int lrow = lane >> 2, lcol = (lane & 3) * 8;

    auto stage = [&](int buf, int k0) {
        for (int c = wave; c < 9; c += 4) {
            if (c < 4) {
                GLD16(A + (size_t)(m0 + c * 16 + lrow) * KDIM + k0 + lcol,
                      As2 + buf * SA_TILE + c * 16 * 32);
            } else {
                GLD16(Bt + (size_t)((c - 4) * 16 + lrow) * KDIM + k0 + lcol,
                      Bs2 + buf * SB_TILE + (c - 4) * 16 * 32);
            }
        }
    };

    stage(0, kbase);
    __syncthreads();
    const int NT = KPART / 32;        // 12
    for (int t = 0; t < NT; t++) {
        if (t + 1 < NT) stage((t + 1) & 1, kbase + (t + 1) * 32);
        const u16* Ap = As2 + (t & 1) * SA_TILE;
        const u16* Bp = Bs2 + (t & 1) * SB_TILE;
        bf16x8 af = *(const bf16x8*)(Ap + (wave * 16 + lm) * 32 + quad * 8);
        #pragma unroll
        for (int bn = 0; bn < 5; bn++) {
            bf16x8 bv = *(const bf16x8*)(Bp + (bn * 16 + lm) * 32 + quad * 8);
            acc[bn] = __builtin_amdgcn_mfma_f32_16x16x32_bf16(af, bv, acc[bn], 0, 0, 0);
        }
        __syncthreads();
    }
    float* Cp = C + (size_t)part * M_TOTAL * 80;
    #pragma unroll
    for (int bn = 0; bn < 5; bn++) {
        int col = bn * 16 + lm;
        float bb = 0.0f;
        if (part == 0) bb = (col < 48) ? b0[col] : ((col < 72) ? b1[col - 48] : 0.0f);
        #pragma unroll
        for (int r = 0; r < 4; r++) {
            int row = m0 + wave * 16 + quad * 4 + r;
            Cp[(size_t)row * 80 + col] = acc[bn][r] + bb;
        }
    }
}

// ============ K2: offsets/aw-GEMM FIRST, then value-GEMM ===================
// Small blocks lead the union grid so they overlap the big-block wavefront
// instead of forming a serial tail after it.
__global__ __launch_bounds__(256, 3) void gemms_kernel(
        const u16* __restrict__ feat_bf, const u16* __restrict__ vp_wt,
        const float* __restrict__ vp_b, u16* __restrict__ v_bf,
        const u16* __restrict__ q_bf, const u16* __restrict__ oaw_wt,
        const float* __restrict__ off_b, const float* __restrict__ aw_b,
        float* __restrict__ oa) {
    __shared__ __align__(16) u16 smem[SMEM_U16];   // 48 KB, shared by both
    int b = blockIdx.x;
    if (b < SMALL_BLOCKS) {
        gemm_small_body(b & 127, b >> 7, smem, q_bf, oaw_wt, off_b, aw_b, oa);
    } else {
        gemm_big_body(b - SMALL_BLOCKS, smem, feat_bf, vp_wt, vp_b, v_bf, 1,
                      nullptr, nullptr);
    }
}

// ============ K4: out-GEMM with residual epilogue ==========================
__global__ __launch_bounds__(256, 3) void outgemm_kernel(
        const u16* __restrict__ s_bf, const u16* __restrict__ out_wt,
        const float* __restrict__ out_b, float* __restrict__ out_f,
        const float* __restrict__ query, const float* __restrict__ gamma) {
    __shared__ __align__(16) u16 smem[SMEM_U16];
    gemm_big_body(blockIdx.x, smem, s_bf, out_wt, out_b, out_f, 0, query, gamma);
}

// ============ K3: softmax(24) + bilinear sampling ==========================
// block 192 = 6 heads x 32 lanes; each thread covers 4 consecutive d's (8 B)
__global__ __launch_bounds__(192) void sample_kernel(
        const float* __restrict__ oa, const float* __restrict__ refp,
        const u16* __restrict__ v, u16* __restrict__ out) {
    int row = blockIdx.x;
    int b = row >> 12;                 // NQ = 4096
    int tid = threadIdx.x;
    __shared__ float s_w[4][24];
    __shared__ int   s_o[4][24];
    __shared__ float s_e[24];
    if (tid < 24) {
        int h = tid >> 2, p = tid & 3;
        float ox = 0.f, oy = 0.f, lg = 0.f;
        #pragma unroll
        for (int part = 0; part < KSPLIT; part++) {
            const float* pp = oa + (size_t)part * M_TOTAL * 80 + (size_t)row * 80;
            ox += pp[h * 8 + p * 2 + 0];
            oy += pp[h * 8 + p * 2 + 1];
            lg += pp[48 + tid];
        }
        float rx = refp[row * 2 + 0], ry = refp[row * 2 + 1];
        float x = (rx + ox * (1.0f / HW_DIM)) * HW_DIM - 0.5f;
        float y = (ry + oy * (1.0f / HW_DIM)) * HW_DIM - 0.5f;
        float fx = floorf(x), fy = floorf(y);
        int x0 = (int)fx, y0 = (int)fy;
        int x1 = x0 + 1, y1 = y0 + 1;
        float wx = x - fx, wy = y - fy;
        float vx0 = (x0 >= 0 && x0 < HW_DIM) ? 1.f : 0.f;
        float vx1 = (x1 >= 0 && x1 < HW_DIM) ? 1.f : 0.f;
        float vy0 = (y0 >= 0 && y0 < HW_DIM) ? 1.f : 0.f;
        float vy1 = (y1 >= 0 && y1 < HW_DIM) ? 1.f : 0.f;
        int xc0 = min(max(x0, 0), HW_DIM - 1), xc1 = min(max(x1, 0), HW_DIM - 1);
        int yc0 = min(max(y0, 0), HW_DIM - 1), yc1 = min(max(y1, 0), HW_DIM - 1);
        int base = b * NV * DIM;
        s_o[0][tid] = base + (yc0 * HW_DIM + xc0) * DIM;
        s_o[1][tid] = base + (yc0 * HW_DIM + xc1) * DIM;
        s_o[2][tid] = base + (yc1 * HW_DIM + xc0) * DIM;
        s_o[3][tid] = base + (yc1 * HW_DIM + xc1) * DIM;
        s_w[0][tid] = (1.f - wy) * (1.f - wx) * vy0 * vx0;
        s_w[1][tid] = (1.f - wy) * wx * vy0 * vx1;
        s_w[2][tid] = wy * (1.f - wx) * vy1 * vx0;
        s_w[3][tid] = wy * wx * vy1 * vx1;
        s_e[tid] = lg;
        float m = s_e[0];
        #pragma unroll
        for (int i = 1; i < 24; i++) m = fmaxf(m, s_e[i]);
        s_e[tid] = expf(lg - m);
    }
    __syncthreads();
    float ssum = 0.0f;
    #pragma unroll
    for (int i = 0; i < 24; i++) ssum += s_e[i];
    float inv = 1.0f / ssum;

    int h = tid >> 5;                  // 0..5
    int d4 = (tid & 31) * 4;           // 0..124
    const u16* vb = v + h * HD + d4;
    float a0 = 0.f, a1 = 0.f, a2 = 0.f, a3 = 0.f;
    #pragma unroll
    for (int p = 0; p < 4; p++) {
        int idx = h * 4 + p;
        float aw = s_e[idx] * inv;
        #pragma unroll
        for (int c = 0; c < 4; c++) {
            uint2 u = *(const uint2*)(vb + s_o[c][idx]);
            float w = aw * s_w[c][idx];
            a0 += w * __uint_as_float(u.x << 16);
            a1 += w * __uint_as_float(u.x & 0xffff0000u);
            a2 += w * __uint_as_float(u.y << 16);
            a3 += w * __uint_as_float(u.y & 0xffff0000u);
        }
    }
    uint2 pack;
    pack.x = (u32)f2bf(a0) | ((u32)f2bf(a1) << 16);
    pack.y = (u32)f2bf(a2) | ((u32)f2bf(a3) << 16);
    *(uint2*)&out[(size_t)row * DIM + h * HD + d4] = pack;
}

extern "C" void kernel_launch(void* const* d_in, const int* in_sizes, int n_in,
                              void* d_out, int out_size, void* d_ws, size_t ws_size,
                              hipStream_t stream) {
    const float* query = (const float*)d_in[0];
    const float* refp  = (const float*)d_in[1];
    const float* feat  = (const float*)d_in[2];
    const float* ln_w  = (const float*)d_in[5];
    const float* ln_b  = (const float*)d_in[6];
    const float* vp_w  = (const float*)d_in[7];
    const float* vp_b  = (const float*)d_in[8];
    const float* off_w = (const float*)d_in[9];
    const float* off_b = (const float*)d_in[10];
    const float* aw_w  = (const float*)d_in[11];
    const float* aw_b  = (const float*)d_in[12];
    const float* out_w = (const float*)d_in[13];
    const float* out_b = (const float*)d_in[14];
    const float* gamma = (const float*)d_in[15];

    const size_t MD = (size_t)M_TOTAL * DIM;      // 6291456
    char* ws = (char*)d_ws;
    u16* q_bf    = (u16*)ws;                 ws += MD * 2;
    u16* feat_bf = (u16*)ws;                 ws += MD * 2;
    u16* v_bf    = (u16*)ws;                 ws += MD * 2;
    u16* s_bf    = (u16*)ws;                 ws += MD * 2;
    u16* vp_wt   = (u16*)ws;                 ws += (size_t)DIM * DIM * 2;
    u16* out_wt  = (u16*)ws;                 ws += (size_t)DIM * DIM * 2;
    u16* oaw_wt  = (u16*)ws;                 ws += (size_t)80 * KDIM * 2;
    float* oa    = (float*)ws;               ws += (size_t)KSPLIT * M_TOTAL * 80 * 4;
    float* out_f = (float*)d_out;

    // K1: LN+feat cvt (2048 blocks) + weight transposes (1224 blocks)
    prep_kernel<<<LN_BLOCKS + TR_BLOCKS, 256, 0, stream>>>(
        query, ln_w, ln_b, q_bf, feat, feat_bf,
        vp_w, vp_wt, out_w, out_wt, off_w, aw_w, oaw_wt);
    // K2: offsets/aw-GEMM (256, first) + value-GEMM (768)
    gemms_kernel<<<SMALL_BLOCKS + GEMM_GRID, 256, 0, stream>>>(
        feat_bf, vp_wt, vp_b, v_bf, q_bf, oaw_wt, off_b, aw_b, oa);
    // K3: sampling
    sample_kernel<<<M_TOTAL, 192, 0, stream>>>(oa, refp, v_bf, s_bf);
    // K4: out = query + gamma * (s @ out_w + out_b)
    outgemm_kernel<<<GEMM_GRID, 256, 0, stream>>>(s_bf, out_wt, out_b, out_f, query, gamma);
}